// Round 4
// baseline (2517.150 us; speedup 1.0000x reference)
//
#include <hip/hip_runtime.h>
#include <math.h>

#define B_  4
#define S_  2048
#define D_  1024
#define H_  16
#define DK_ 64
#define NR_ (B_ * S_)   // 8192 rows

typedef _Float16 half8  __attribute__((ext_vector_type(8)));
typedef float    floatx4 __attribute__((ext_vector_type(4)));

// ---------------------------------------------------------------------------
// GEMM: out = X @ W^T via split-f16 MFMA (fp32-accurate).
// X:[N x K] row-major, W:[M x K] row-major. N=8192, K=M=1024.
// x = hi + lo (f16 each, ~22 mantissa bits); C += Xhi*Whi + Xhi*Wlo + Xlo*Whi.
// Block: 256 threads (4 waves), tile 128(n) x 64(m), BK=32.
// Wave w owns n-rows [w*32, w*32+32): 2 x 4 tiles of 16x16 via
// mfma_f32_16x16x32_f16. Fragment layouts (HW-verified, dtype-independent):
//   A/B operand: [free_idx = lane&15][k = (lane>>4)*8 + j], j in [0,8)
//   C/D:         row = (lane>>4)*4 + reg, col = lane&15
// split=1: scatter output into head-split [B,H,S,DK]; split=0: [N x M].
// ---------------------------------------------------------------------------
#define GBN 128
#define GBM 64
#define GBK 32
#define LDH 40   // LDS row stride in halves: 80 B, keeps 16 B alignment, breaks pow2

__global__ __launch_bounds__(256)
void gemm_xwt_mfma(const float* __restrict__ X, const float* __restrict__ W,
                   float* __restrict__ out, int split) {
    __shared__ __align__(16) _Float16 Xhi[GBN][LDH];
    __shared__ __align__(16) _Float16 Xlo[GBN][LDH];
    __shared__ __align__(16) _Float16 Whi[GBM][LDH];
    __shared__ __align__(16) _Float16 Wlo[GBM][LDH];
    const int K = D_;

    const int tid  = threadIdx.x;
    const int wave = tid >> 6;
    const int lane = tid & 63;
    const int row16 = lane & 15;    // free index within a 16x16 MFMA tile
    const int quad  = lane >> 4;    // k-group selector
    const int n0 = blockIdx.x * GBN;
    const int m0 = blockIdx.y * GBM;

    floatx4 acc[2][4];
    const floatx4 zero4 = {0.f, 0.f, 0.f, 0.f};
    #pragma unroll
    for (int i = 0; i < 2; ++i)
        #pragma unroll
        for (int j = 0; j < 4; ++j) acc[i][j] = zero4;

    for (int k0 = 0; k0 < K; k0 += GBK) {
        __syncthreads();   // previous iteration's reads done before overwrite
        // stage X tile 128x32: 1024 float4, 4 per thread; split to hi/lo f16
        #pragma unroll
        for (int i = 0; i < 4; ++i) {
            const int t   = i * 256 + tid;
            const int row = t >> 3;             // 8 float4 per row
            const int c4  = (t & 7) << 2;
            float4 xv = *(const float4*)(X + (size_t)(n0 + row) * K + k0 + c4);
            float f[4] = {xv.x, xv.y, xv.z, xv.w};
            #pragma unroll
            for (int c = 0; c < 4; ++c) {
                _Float16 h = (_Float16)f[c];
                Xhi[row][c4 + c] = h;
                Xlo[row][c4 + c] = (_Float16)(f[c] - (float)h);
            }
        }
        // stage W tile 64x32: 512 float4, 2 per thread
        #pragma unroll
        for (int i = 0; i < 2; ++i) {
            const int t   = i * 256 + tid;
            const int row = t >> 3;
            const int c4  = (t & 7) << 2;
            float4 wv = *(const float4*)(W + (size_t)(m0 + row) * K + k0 + c4);
            float f[4] = {wv.x, wv.y, wv.z, wv.w};
            #pragma unroll
            for (int c = 0; c < 4; ++c) {
                _Float16 h = (_Float16)f[c];
                Whi[row][c4 + c] = h;
                Wlo[row][c4 + c] = (_Float16)(f[c] - (float)h);
            }
        }
        __syncthreads();

        // fragments: 16 B contiguous LDS reads (aligned: row*80 + quad*16)
        half8 a_hi[2], a_lo[2], b_hi[4], b_lo[4];
        #pragma unroll
        for (int ni = 0; ni < 2; ++ni) {
            const int r = wave * 32 + ni * 16 + row16;
            a_hi[ni] = *(const half8*)&Xhi[r][quad * 8];
            a_lo[ni] = *(const half8*)&Xlo[r][quad * 8];
        }
        #pragma unroll
        for (int mj = 0; mj < 4; ++mj) {
            const int r = mj * 16 + row16;
            b_hi[mj] = *(const half8*)&Whi[r][quad * 8];
            b_lo[mj] = *(const half8*)&Wlo[r][quad * 8];
        }

        #pragma unroll
        for (int ni = 0; ni < 2; ++ni)
            #pragma unroll
            for (int mj = 0; mj < 4; ++mj) {
                acc[ni][mj] = __builtin_amdgcn_mfma_f32_16x16x32_f16(
                    a_hi[ni], b_hi[mj], acc[ni][mj], 0, 0, 0);
                acc[ni][mj] = __builtin_amdgcn_mfma_f32_16x16x32_f16(
                    a_hi[ni], b_lo[mj], acc[ni][mj], 0, 0, 0);
                acc[ni][mj] = __builtin_amdgcn_mfma_f32_16x16x32_f16(
                    a_lo[ni], b_hi[mj], acc[ni][mj], 0, 0, 0);
            }
    }

    #pragma unroll
    for (int ni = 0; ni < 2; ++ni)
        #pragma unroll
        for (int mj = 0; mj < 4; ++mj)
            #pragma unroll
            for (int rg = 0; rg < 4; ++rg) {
                const int n = n0 + wave * 32 + ni * 16 + quad * 4 + rg;
                const int m = m0 + mj * 16 + row16;
                size_t off;
                if (split) {
                    const int b  = n >> 11;       // n / S_
                    const int s  = n & (S_ - 1);
                    const int h  = m >> 6;        // m / DK_
                    const int dk = m & 63;
                    off = (((size_t)b * H_ + h) * S_ + s) * DK_ + dk;
                } else {
                    off = (size_t)n * D_ + m;
                }
                out[off] = acc[ni][mj][rg];
            }
}

// ---------------------------------------------------------------------------
// Flash-style causal attention (unchanged fp32 baseline). One block = one
// (b,h) x 64-row Q tile. Thread (r=tid>>2, p=tid&3) owns Q row r, dim segment
// [p*16,p*16+16), score columns c%4==p. K/V tiles in LDS; online softmax.
// All width-4 shuffles stay inside one 64-lane wave.
// ---------------------------------------------------------------------------
#define TQ 64
#define TK 64

__global__ __launch_bounds__(256)
void attn_causal(const float* __restrict__ Qh, const float* __restrict__ Kh,
                 const float* __restrict__ Vh, float* __restrict__ A) {
    __shared__ float Ks[TK][DK_];
    __shared__ float Vs[TK][DK_];

    const int bh = blockIdx.y;
    const int qt = blockIdx.x;
    const int q0 = qt * TQ;
    const float* Qb = Qh + (size_t)bh * S_ * DK_;
    const float* Kb = Kh + (size_t)bh * S_ * DK_;
    const float* Vb = Vh + (size_t)bh * S_ * DK_;

    const int tid = threadIdx.x;
    const int r = tid >> 2;
    const int p = tid & 3;
    const int qg = q0 + r;

    float qreg[16];
    {
        const float4* src = (const float4*)(Qb + (size_t)qg * DK_ + p * 16);
        #pragma unroll
        for (int i = 0; i < 4; ++i) {
            float4 t = src[i];
            qreg[4 * i + 0] = t.x * 0.125f;
            qreg[4 * i + 1] = t.y * 0.125f;
            qreg[4 * i + 2] = t.z * 0.125f;
            qreg[4 * i + 3] = t.w * 0.125f;
        }
    }

    float O[16];
    #pragma unroll
    for (int i = 0; i < 16; ++i) O[i] = 0.f;
    float mrun = -INFINITY, lrun = 0.f;

    for (int kt = 0; kt <= qt; ++kt) {
        const int k0 = kt * TK;
        __syncthreads();
        #pragma unroll
        for (int i = 0; i < 4; ++i) {
            const int f = i * 256 + tid;
            const int rr = f >> 4;
            const int dd = (f & 15) << 2;
            *(float4*)&Ks[rr][dd] = *(const float4*)(Kb + (size_t)(k0 + rr) * DK_ + dd);
            *(float4*)&Vs[rr][dd] = *(const float4*)(Vb + (size_t)(k0 + rr) * DK_ + dd);
        }
        __syncthreads();

        float sc[16];
        for (int c = 0; c < TK; ++c) {
            const float* kr = &Ks[c][p * 16];
            float s = 0.f;
            #pragma unroll
            for (int dd = 0; dd < 16; dd += 4) {
                float4 k4 = *(const float4*)(kr + dd);
                s = fmaf(qreg[dd + 0], k4.x, s);
                s = fmaf(qreg[dd + 1], k4.y, s);
                s = fmaf(qreg[dd + 2], k4.z, s);
                s = fmaf(qreg[dd + 3], k4.w, s);
            }
            s += __shfl_xor(s, 1, 4);
            s += __shfl_xor(s, 2, 4);
            if ((c & 3) == p) sc[c >> 2] = s;
        }

        #pragma unroll
        for (int cc = 0; cc < 16; ++cc) {
            const int kg = k0 + cc * 4 + p;
            if (kg > qg) sc[cc] = -INFINITY;
        }

        float mloc = -INFINITY;
        #pragma unroll
        for (int cc = 0; cc < 16; ++cc) mloc = fmaxf(mloc, sc[cc]);
        mloc = fmaxf(mloc, __shfl_xor(mloc, 1, 4));
        mloc = fmaxf(mloc, __shfl_xor(mloc, 2, 4));
        const float mnew = fmaxf(mrun, mloc);
        const float alpha = __expf(mrun - mnew);
        float lloc = 0.f;
        #pragma unroll
        for (int cc = 0; cc < 16; ++cc) {
            const float pv = __expf(sc[cc] - mnew);
            sc[cc] = pv;
            lloc += pv;
        }
        lloc += __shfl_xor(lloc, 1, 4);
        lloc += __shfl_xor(lloc, 2, 4);
        lrun = alpha * lrun + lloc;
        mrun = mnew;
        #pragma unroll
        for (int i = 0; i < 16; ++i) O[i] *= alpha;

        for (int cc = 0; cc < 16; ++cc) {
            #pragma unroll
            for (int sp = 0; sp < 4; ++sp) {
                const float pval = __shfl(sc[cc], sp, 4);
                const float* vr = &Vs[cc * 4 + sp][p * 16];
                #pragma unroll
                for (int dd = 0; dd < 16; dd += 4) {
                    float4 v4 = *(const float4*)(vr + dd);
                    O[dd + 0] = fmaf(pval, v4.x, O[dd + 0]);
                    O[dd + 1] = fmaf(pval, v4.y, O[dd + 1]);
                    O[dd + 2] = fmaf(pval, v4.z, O[dd + 2]);
                    O[dd + 3] = fmaf(pval, v4.w, O[dd + 3]);
                }
            }
        }
    }

    const float inv = 1.f / lrun;
    const int b = bh >> 4;
    const int h = bh & 15;
    float* dst = A + ((size_t)b * S_ + qg) * D_ + h * DK_ + p * 16;
    #pragma unroll
    for (int i = 0; i < 4; ++i) {
        float4 o4 = make_float4(O[4 * i + 0] * inv, O[4 * i + 1] * inv,
                                O[4 * i + 2] * inv, O[4 * i + 3] * inv);
        *(float4*)(dst + 4 * i) = o4;
    }
}

// ---------------------------------------------------------------------------
extern "C" void kernel_launch(void* const* d_in, const int* in_sizes, int n_in,
                              void* d_out, int out_size, void* d_ws, size_t ws_size,
                              hipStream_t stream) {
    const float* q  = (const float*)d_in[0];
    const float* k  = (const float*)d_in[1];
    const float* v  = (const float*)d_in[2];
    const float* Wq = (const float*)d_in[3];
    const float* Wk = (const float*)d_in[4];
    const float* Wv = (const float*)d_in[5];
    const float* Wo = (const float*)d_in[6];
    float* out = (float*)d_out;

    const size_t SZ = (size_t)B_ * S_ * D_;   // 8,388,608 floats = 32 MB
    float* ws = (float*)d_ws;
    float* Qh = ws;            // [B,H,S,DK]
    float* Kh = ws + SZ;       // [B,H,S,DK]
    float* Vh = ws + 2 * SZ;   // [B,H,S,DK]
    float* A  = ws + 3 * SZ;   // [B,S,D] attention output (pre-Wo)

    dim3 gb(NR_ / GBN, D_ / GBM);   // 64 x 16
    gemm_xwt_mfma<<<gb, 256, 0, stream>>>(q, Wq, Qh, 1);
    gemm_xwt_mfma<<<gb, 256, 0, stream>>>(k, Wk, Kh, 1);
    gemm_xwt_mfma<<<gb, 256, 0, stream>>>(v, Wv, Vh, 1);

    dim3 ga(S_ / TQ, B_ * H_);      // 32 x 64
    attn_causal<<<ga, 256, 0, stream>>>(Qh, Kh, Vh, A);

    gemm_xwt_mfma<<<gb, 256, 0, stream>>>(A, Wo, out, 0);
}

// Round 5
// 803.595 us; speedup vs baseline: 3.1324x; 3.1324x over previous
//
#include <hip/hip_runtime.h>
#include <math.h>
#include <stdint.h>

#define B_  4
#define S_  2048
#define D_  1024
#define H_  16
#define DK_ 64
#define NR_ (B_ * S_)   // 8192 rows

typedef _Float16 half8  __attribute__((ext_vector_type(8)));
typedef float    floatx4 __attribute__((ext_vector_type(4)));

// ---------------------------------------------------------------------------
// GEMM: out = X @ W^T via split-f16 MFMA (fp32-accurate). Validated round 4.
// Epilogue modes:
//   0: fp32 [N x M] row-major                      (Wo projection -> d_out)
//   1: packed u32 {lo16,hi16} f16 split, [B,H,S,DK] (Q,K projections)
//   2: fp32 transposed head-split [B,H,DK,S]        (V projection)
// ---------------------------------------------------------------------------
#define GBN 128
#define GBM 64
#define GBK 32
#define LDH 40

__global__ __launch_bounds__(256)
void gemm_xwt_mfma(const float* __restrict__ X, const float* __restrict__ W,
                   void* __restrict__ outp, int mode) {
    __shared__ __align__(16) _Float16 Xhi[GBN][LDH];
    __shared__ __align__(16) _Float16 Xlo[GBN][LDH];
    __shared__ __align__(16) _Float16 Whi[GBM][LDH];
    __shared__ __align__(16) _Float16 Wlo[GBM][LDH];
    const int K = D_;

    const int tid  = threadIdx.x;
    const int wave = tid >> 6;
    const int lane = tid & 63;
    const int row16 = lane & 15;
    const int quad  = lane >> 4;
    const int n0 = blockIdx.x * GBN;
    const int m0 = blockIdx.y * GBM;

    floatx4 acc[2][4];
    const floatx4 zero4 = {0.f, 0.f, 0.f, 0.f};
    #pragma unroll
    for (int i = 0; i < 2; ++i)
        #pragma unroll
        for (int j = 0; j < 4; ++j) acc[i][j] = zero4;

    for (int k0 = 0; k0 < K; k0 += GBK) {
        __syncthreads();
        #pragma unroll
        for (int i = 0; i < 4; ++i) {
            const int t   = i * 256 + tid;
            const int row = t >> 3;
            const int c4  = (t & 7) << 2;
            float4 xv = *(const float4*)(X + (size_t)(n0 + row) * K + k0 + c4);
            float f[4] = {xv.x, xv.y, xv.z, xv.w};
            #pragma unroll
            for (int c = 0; c < 4; ++c) {
                _Float16 h = (_Float16)f[c];
                Xhi[row][c4 + c] = h;
                Xlo[row][c4 + c] = (_Float16)(f[c] - (float)h);
            }
        }
        #pragma unroll
        for (int i = 0; i < 2; ++i) {
            const int t   = i * 256 + tid;
            const int row = t >> 3;
            const int c4  = (t & 7) << 2;
            float4 wv = *(const float4*)(W + (size_t)(m0 + row) * K + k0 + c4);
            float f[4] = {wv.x, wv.y, wv.z, wv.w};
            #pragma unroll
            for (int c = 0; c < 4; ++c) {
                _Float16 h = (_Float16)f[c];
                Whi[row][c4 + c] = h;
                Wlo[row][c4 + c] = (_Float16)(f[c] - (float)h);
            }
        }
        __syncthreads();

        half8 a_hi[2], a_lo[2], b_hi[4], b_lo[4];
        #pragma unroll
        for (int ni = 0; ni < 2; ++ni) {
            const int r = wave * 32 + ni * 16 + row16;
            a_hi[ni] = *(const half8*)&Xhi[r][quad * 8];
            a_lo[ni] = *(const half8*)&Xlo[r][quad * 8];
        }
        #pragma unroll
        for (int mj = 0; mj < 4; ++mj) {
            const int r = mj * 16 + row16;
            b_hi[mj] = *(const half8*)&Whi[r][quad * 8];
            b_lo[mj] = *(const half8*)&Wlo[r][quad * 8];
        }

        #pragma unroll
        for (int ni = 0; ni < 2; ++ni)
            #pragma unroll
            for (int mj = 0; mj < 4; ++mj) {
                acc[ni][mj] = __builtin_amdgcn_mfma_f32_16x16x32_f16(
                    a_hi[ni], b_hi[mj], acc[ni][mj], 0, 0, 0);
                acc[ni][mj] = __builtin_amdgcn_mfma_f32_16x16x32_f16(
                    a_hi[ni], b_lo[mj], acc[ni][mj], 0, 0, 0);
                acc[ni][mj] = __builtin_amdgcn_mfma_f32_16x16x32_f16(
                    a_lo[ni], b_hi[mj], acc[ni][mj], 0, 0, 0);
            }
    }

    #pragma unroll
    for (int ni = 0; ni < 2; ++ni)
        #pragma unroll
        for (int mj = 0; mj < 4; ++mj)
            #pragma unroll
            for (int rg = 0; rg < 4; ++rg) {
                const int n = n0 + wave * 32 + ni * 16 + quad * 4 + rg;
                const int m = m0 + mj * 16 + row16;
                const float v = acc[ni][mj][rg];
                if (mode == 0) {
                    ((float*)outp)[(size_t)n * D_ + m] = v;
                } else {
                    const int b  = n >> 11;
                    const int s  = n & (S_ - 1);
                    const int h  = m >> 6;
                    const int dk = m & 63;
                    if (mode == 1) {
                        union { _Float16 h16; uint16_t u; } hi, lo;
                        hi.h16 = (_Float16)v;
                        lo.h16 = (_Float16)(v - (float)hi.h16);
                        uint32_t u = ((uint32_t)lo.u << 16) | (uint32_t)hi.u;
                        ((uint32_t*)outp)[(((size_t)b * H_ + h) * S_ + s) * DK_ + dk] = u;
                    } else {
                        ((float*)outp)[(((size_t)b * H_ + h) * DK_ + dk) * S_ + s] = v;
                    }
                }
            }
}

// ---------------------------------------------------------------------------
// MFMA flash attention. Block = (b,h) x 64-row Q tile, 4 waves; wave owns 16
// q-rows. Scores = split-f16 MFMA (fp32-accurate); softmax in fp32; P,V in
// f16 for PV. P goes C-layout -> LDS -> A-layout (wave-private, no barrier).
// V comes pre-transposed [B,H,DK,S] so B-fragments are contiguous b128 reads.
// LDS row stride 72 halves: bank = 4*(c+quad) mod 32 -> even 8-word/bank.
// ---------------------------------------------------------------------------
__global__ __launch_bounds__(256)
void attn_mfma(const uint32_t* __restrict__ Qhl, const uint32_t* __restrict__ Khl,
               const float* __restrict__ Vt, float* __restrict__ A) {
    __shared__ __align__(16) _Float16 KhiL[64][72];
    __shared__ __align__(16) _Float16 KloL[64][72];
    __shared__ __align__(16) _Float16 VtL[64][72];
    __shared__ __align__(16) _Float16 Pw[4][16][72];

    const int bh = blockIdx.y;
    const int qt = (gridDim.x - 1) - blockIdx.x;   // heavy q-tiles dispatch first
    const int q0 = qt * 64;
    const int tid  = threadIdx.x;
    const int wave = tid >> 6;
    const int lane = tid & 63;
    const int c    = lane & 15;
    const int quad = lane >> 4;

    // Q fragments for the wave's 16 rows, resident across the whole K-loop
    half8 qhi[2], qlo[2];
    {
        const uint32_t* Qrow = Qhl + ((size_t)bh * S_ + q0 + wave * 16 + c) * DK_;
        #pragma unroll
        for (int ks = 0; ks < 2; ++ks) {
            uint32_t u[8];
            *(uint4*)&u[0] = *(const uint4*)(Qrow + ks * 32 + quad * 8);
            *(uint4*)&u[4] = *(const uint4*)(Qrow + ks * 32 + quad * 8 + 4);
            union { half8 v; uint16_t s[8]; } hi, lo;
            #pragma unroll
            for (int j = 0; j < 8; ++j) {
                hi.s[j] = (uint16_t)(u[j] & 0xffffu);
                lo.s[j] = (uint16_t)(u[j] >> 16);
            }
            qhi[ks] = hi.v; qlo[ks] = lo.v;
        }
    }

    floatx4 acc_o[4];
    const floatx4 zero4 = {0.f, 0.f, 0.f, 0.f};
    #pragma unroll
    for (int d = 0; d < 4; ++d) acc_o[d] = zero4;
    float mrun[4] = {-INFINITY, -INFINITY, -INFINITY, -INFINITY};
    float lrun[4] = {0.f, 0.f, 0.f, 0.f};

    const uint32_t* Kb = Khl + (size_t)bh * S_ * DK_;
    const float*    Vb = Vt  + (size_t)bh * DK_ * S_;

    for (int kt = 0; kt <= qt; ++kt) {
        const int k0 = kt * 64;
        __syncthreads();   // all waves done reading previous K/V tiles
        {   // stage K tile: unpack u32 -> hi/lo f16
            const int row = tid >> 2, dk0 = (tid & 3) * 16;
            const uint4* src = (const uint4*)(Kb + (size_t)(k0 + row) * DK_ + dk0);
            #pragma unroll
            for (int i = 0; i < 4; ++i) {
                uint4 u4 = src[i];
                uint32_t uu[4] = {u4.x, u4.y, u4.z, u4.w};
                union { uint2 v; uint16_t s[4]; } hi, lo;
                #pragma unroll
                for (int j = 0; j < 4; ++j) {
                    hi.s[j] = (uint16_t)(uu[j] & 0xffffu);
                    lo.s[j] = (uint16_t)(uu[j] >> 16);
                }
                *(uint2*)&KhiL[row][dk0 + 4 * i] = hi.v;
                *(uint2*)&KloL[row][dk0 + 4 * i] = lo.v;
            }
        }
        {   // stage V^T tile: fp32 -> f16
            const int dkr = tid >> 2, s0 = (tid & 3) * 16;
            const float4* src = (const float4*)(Vb + (size_t)dkr * S_ + k0 + s0);
            #pragma unroll
            for (int i = 0; i < 4; ++i) {
                float4 f = src[i];
                union { uint2 v; _Float16 h[4]; } t;
                t.h[0] = (_Float16)f.x; t.h[1] = (_Float16)f.y;
                t.h[2] = (_Float16)f.z; t.h[3] = (_Float16)f.w;
                *(uint2*)&VtL[dkr][s0 + 4 * i] = t.v;
            }
        }
        __syncthreads();

        // scores: S = Q K^T (split-f16: hi*hi + hi*lo + lo*hi)
        floatx4 sc[4];
        #pragma unroll
        for (int t = 0; t < 4; ++t) {
            floatx4 s4 = zero4;
            #pragma unroll
            for (int ks = 0; ks < 2; ++ks) {
                half8 bh8 = *(const half8*)&KhiL[t * 16 + c][ks * 32 + quad * 8];
                half8 bl8 = *(const half8*)&KloL[t * 16 + c][ks * 32 + quad * 8];
                s4 = __builtin_amdgcn_mfma_f32_16x16x32_f16(qhi[ks], bh8, s4, 0, 0, 0);
                s4 = __builtin_amdgcn_mfma_f32_16x16x32_f16(qhi[ks], bl8, s4, 0, 0, 0);
                s4 = __builtin_amdgcn_mfma_f32_16x16x32_f16(qlo[ks], bh8, s4, 0, 0, 0);
            }
            sc[t] = s4;
        }

        // scale + causal mask (C layout: row = quad*4+reg, col = lane&15)
        const int qrow0 = q0 + wave * 16 + quad * 4;
        #pragma unroll
        for (int t = 0; t < 4; ++t) {
            const int col = k0 + t * 16 + c;
            #pragma unroll
            for (int r = 0; r < 4; ++r) {
                const float s = sc[t][r] * 0.125f;
                sc[t][r] = (col <= qrow0 + r) ? s : -INFINITY;
            }
        }

        // online softmax, row state per reg (row spread over 16 lanes)
        #pragma unroll
        for (int r = 0; r < 4; ++r) {
            float mx = fmaxf(fmaxf(sc[0][r], sc[1][r]), fmaxf(sc[2][r], sc[3][r]));
            mx = fmaxf(mx, __shfl_xor(mx, 1, 16));
            mx = fmaxf(mx, __shfl_xor(mx, 2, 16));
            mx = fmaxf(mx, __shfl_xor(mx, 4, 16));
            mx = fmaxf(mx, __shfl_xor(mx, 8, 16));
            const float mnew  = fmaxf(mrun[r], mx);
            const float alpha = __expf(mrun[r] - mnew);
            float ls = 0.f;
            #pragma unroll
            for (int t = 0; t < 4; ++t) {
                const float p = __expf(sc[t][r] - mnew);
                sc[t][r] = p;
                ls += p;
            }
            ls += __shfl_xor(ls, 1, 16);
            ls += __shfl_xor(ls, 2, 16);
            ls += __shfl_xor(ls, 4, 16);
            ls += __shfl_xor(ls, 8, 16);
            lrun[r] = alpha * lrun[r] + ls;
            mrun[r] = mnew;
            #pragma unroll
            for (int d = 0; d < 4; ++d) acc_o[d][r] *= alpha;
        }

        // P: C-layout -> wave-private LDS (f16); same-wave RAW, no barrier
        #pragma unroll
        for (int t = 0; t < 4; ++t)
            #pragma unroll
            for (int r = 0; r < 4; ++r)
                Pw[wave][quad * 4 + r][t * 16 + c] = (_Float16)sc[t][r];

        // O += P V  (A = P rows, B = V^T rows)
        half8 pa0 = *(const half8*)&Pw[wave][c][quad * 8];
        half8 pa1 = *(const half8*)&Pw[wave][c][32 + quad * 8];
        #pragma unroll
        for (int d = 0; d < 4; ++d) {
            half8 vb0 = *(const half8*)&VtL[d * 16 + c][quad * 8];
            half8 vb1 = *(const half8*)&VtL[d * 16 + c][32 + quad * 8];
            acc_o[d] = __builtin_amdgcn_mfma_f32_16x16x32_f16(pa0, vb0, acc_o[d], 0, 0, 0);
            acc_o[d] = __builtin_amdgcn_mfma_f32_16x16x32_f16(pa1, vb1, acc_o[d], 0, 0, 0);
        }
    }

    // normalize + write A[B,S,D]
    const int b = bh >> 4, h = bh & 15;
    #pragma unroll
    for (int r = 0; r < 4; ++r) {
        const float inv = 1.f / lrun[r];
        const int qr = q0 + wave * 16 + quad * 4 + r;
        float* dst = A + ((size_t)b * S_ + qr) * D_ + h * DK_;
        #pragma unroll
        for (int d = 0; d < 4; ++d)
            dst[d * 16 + c] = acc_o[d][r] * inv;
    }
}

// ---------------------------------------------------------------------------
extern "C" void kernel_launch(void* const* d_in, const int* in_sizes, int n_in,
                              void* d_out, int out_size, void* d_ws, size_t ws_size,
                              hipStream_t stream) {
    const float* q  = (const float*)d_in[0];
    const float* k  = (const float*)d_in[1];
    const float* v  = (const float*)d_in[2];
    const float* Wq = (const float*)d_in[3];
    const float* Wk = (const float*)d_in[4];
    const float* Wv = (const float*)d_in[5];
    const float* Wo = (const float*)d_in[6];
    float* out = (float*)d_out;

    const size_t SZ = (size_t)B_ * S_ * D_;   // 8,388,608 elements
    float* wsf = (float*)d_ws;
    uint32_t* Qhl = (uint32_t*)wsf;            // packed f16 hi/lo [B,H,S,DK]
    uint32_t* Khl = (uint32_t*)(wsf + SZ);     // packed f16 hi/lo [B,H,S,DK]
    float*    Vt  = wsf + 2 * SZ;              // fp32 [B,H,DK,S]
    float*    A   = wsf + 3 * SZ;              // fp32 [B,S,D]

    dim3 gb(NR_ / GBN, D_ / GBM);   // 64 x 16
    gemm_xwt_mfma<<<gb, 256, 0, stream>>>(q, Wq, Qhl, 1);
    gemm_xwt_mfma<<<gb, 256, 0, stream>>>(k, Wk, Khl, 1);
    gemm_xwt_mfma<<<gb, 256, 0, stream>>>(v, Wv, Vt, 2);

    dim3 ga(S_ / 64, B_ * H_);      // 32 x 64
    attn_mfma<<<ga, 256, 0, stream>>>(Qhl, Khl, Vt, A);

    gemm_xwt_mfma<<<gb, 256, 0, stream>>>(A, Wo, out, 0);
}

// Round 6
// 801.362 us; speedup vs baseline: 3.1411x; 1.0028x over previous
//
#include <hip/hip_runtime.h>
#include <math.h>
#include <stdint.h>

#define B_  4
#define S_  2048
#define D_  1024
#define H_  16
#define DK_ 64
#define NR_ (B_ * S_)   // 8192 rows

typedef _Float16 half8  __attribute__((ext_vector_type(8)));
typedef float    floatx4 __attribute__((ext_vector_type(4)));

// ---------------------------------------------------------------------------
// GEMM: out = X @ W^T via split-f16 MFMA (fp32-accurate). Validated round 4/5.
// Epilogue modes:
//   0: fp32 [N x M] row-major                       (Wo projection -> d_out)
//   1: packed u32 {lo16,hi16} f16 split, [B,H,S,DK]  (Q,K projections)
//   2: fp32 transposed head-split [B,H,DK,S]         (V projection; float4
//      stores over the 4 consecutive-s acc regs -> fully coalesced)
// ---------------------------------------------------------------------------
#define GBN 128
#define GBM 64
#define GBK 32
#define LDH 40

__global__ __launch_bounds__(256)
void gemm_xwt_mfma(const float* __restrict__ X, const float* __restrict__ W,
                   void* __restrict__ outp, int mode) {
    __shared__ __align__(16) _Float16 Xhi[GBN][LDH];
    __shared__ __align__(16) _Float16 Xlo[GBN][LDH];
    __shared__ __align__(16) _Float16 Whi[GBM][LDH];
    __shared__ __align__(16) _Float16 Wlo[GBM][LDH];
    const int K = D_;

    const int tid  = threadIdx.x;
    const int wave = tid >> 6;
    const int lane = tid & 63;
    const int row16 = lane & 15;
    const int quad  = lane >> 4;
    const int n0 = blockIdx.x * GBN;
    const int m0 = blockIdx.y * GBM;

    floatx4 acc[2][4];
    const floatx4 zero4 = {0.f, 0.f, 0.f, 0.f};
    #pragma unroll
    for (int i = 0; i < 2; ++i)
        #pragma unroll
        for (int j = 0; j < 4; ++j) acc[i][j] = zero4;

    for (int k0 = 0; k0 < K; k0 += GBK) {
        __syncthreads();
        #pragma unroll
        for (int i = 0; i < 4; ++i) {
            const int t   = i * 256 + tid;
            const int row = t >> 3;
            const int c4  = (t & 7) << 2;
            float4 xv = *(const float4*)(X + (size_t)(n0 + row) * K + k0 + c4);
            float f[4] = {xv.x, xv.y, xv.z, xv.w};
            #pragma unroll
            for (int c = 0; c < 4; ++c) {
                _Float16 h = (_Float16)f[c];
                Xhi[row][c4 + c] = h;
                Xlo[row][c4 + c] = (_Float16)(f[c] - (float)h);
            }
        }
        #pragma unroll
        for (int i = 0; i < 2; ++i) {
            const int t   = i * 256 + tid;
            const int row = t >> 3;
            const int c4  = (t & 7) << 2;
            float4 wv = *(const float4*)(W + (size_t)(m0 + row) * K + k0 + c4);
            float f[4] = {wv.x, wv.y, wv.z, wv.w};
            #pragma unroll
            for (int c = 0; c < 4; ++c) {
                _Float16 h = (_Float16)f[c];
                Whi[row][c4 + c] = h;
                Wlo[row][c4 + c] = (_Float16)(f[c] - (float)h);
            }
        }
        __syncthreads();

        half8 a_hi[2], a_lo[2], b_hi[4], b_lo[4];
        #pragma unroll
        for (int ni = 0; ni < 2; ++ni) {
            const int r = wave * 32 + ni * 16 + row16;
            a_hi[ni] = *(const half8*)&Xhi[r][quad * 8];
            a_lo[ni] = *(const half8*)&Xlo[r][quad * 8];
        }
        #pragma unroll
        for (int mj = 0; mj < 4; ++mj) {
            const int r = mj * 16 + row16;
            b_hi[mj] = *(const half8*)&Whi[r][quad * 8];
            b_lo[mj] = *(const half8*)&Wlo[r][quad * 8];
        }

        #pragma unroll
        for (int ni = 0; ni < 2; ++ni)
            #pragma unroll
            for (int mj = 0; mj < 4; ++mj) {
                acc[ni][mj] = __builtin_amdgcn_mfma_f32_16x16x32_f16(
                    a_hi[ni], b_hi[mj], acc[ni][mj], 0, 0, 0);
                acc[ni][mj] = __builtin_amdgcn_mfma_f32_16x16x32_f16(
                    a_hi[ni], b_lo[mj], acc[ni][mj], 0, 0, 0);
                acc[ni][mj] = __builtin_amdgcn_mfma_f32_16x16x32_f16(
                    a_lo[ni], b_hi[mj], acc[ni][mj], 0, 0, 0);
            }
    }

    #pragma unroll
    for (int ni = 0; ni < 2; ++ni)
        #pragma unroll
        for (int mj = 0; mj < 4; ++mj) {
            if (mode == 2) {
                // 4 acc regs = 4 consecutive s values -> one float4 store
                const int s  = n0 + wave * 32 + ni * 16 + quad * 4;
                const int b  = s >> 11;
                const int sr = s & (S_ - 1);
                const int m  = m0 + mj * 16 + row16;
                const int h  = m >> 6;
                const int dk = m & 63;
                float4 v4 = make_float4(acc[ni][mj][0], acc[ni][mj][1],
                                        acc[ni][mj][2], acc[ni][mj][3]);
                *(float4*)((float*)outp +
                           (((size_t)b * H_ + h) * DK_ + dk) * S_ + sr) = v4;
            } else {
                #pragma unroll
                for (int rg = 0; rg < 4; ++rg) {
                    const int n = n0 + wave * 32 + ni * 16 + quad * 4 + rg;
                    const int m = m0 + mj * 16 + row16;
                    const float v = acc[ni][mj][rg];
                    if (mode == 0) {
                        ((float*)outp)[(size_t)n * D_ + m] = v;
                    } else {
                        const int b  = n >> 11;
                        const int s  = n & (S_ - 1);
                        const int h  = m >> 6;
                        const int dk = m & 63;
                        union { _Float16 h16; uint16_t u; } hi, lo;
                        hi.h16 = (_Float16)v;
                        lo.h16 = (_Float16)(v - (float)hi.h16);
                        uint32_t u = ((uint32_t)lo.u << 16) | (uint32_t)hi.u;
                        ((uint32_t*)outp)[(((size_t)b * H_ + h) * S_ + s) * DK_ + dk] = u;
                    }
                }
            }
        }
}

// ---------------------------------------------------------------------------
// MFMA flash attention, v2. Block = (b,h) x 128-row Q tile, 4 waves; wave owns
// 32 q-rows (2 x 16-row fragments). K-tile 64. Software-pipelined staging:
// next tile's global loads issue before compute, LDS write after. Chunked LDS
// layouts [chunk][row][8] -> b128 ops tile all 32 banks. Split-f16 scores,
// f16 P/V for PV. Causal skip per wave-rowset (wave-uniform guard).
// ---------------------------------------------------------------------------
__global__ __launch_bounds__(256)
void attn_mfma(const uint32_t* __restrict__ Qhl, const uint32_t* __restrict__ Khl,
               const float* __restrict__ Vt, float* __restrict__ A) {
    __shared__ __align__(16) _Float16 KhiC[8][64][8];
    __shared__ __align__(16) _Float16 KloC[8][64][8];
    __shared__ __align__(16) _Float16 VC[8][64][8];
    __shared__ __align__(16) _Float16 PC[4][2][8][16][8];   // wave, rowset

    const int bh = blockIdx.y;
    const int qt = (int)(gridDim.x - 1) - (int)blockIdx.x;  // heavy tiles first
    const int q0 = qt * 128;
    const int tid  = threadIdx.x;
    const int wave = tid >> 6;
    const int lane = tid & 63;
    const int c    = lane & 15;
    const int quad = lane >> 4;
    const int ktmax = 2 * qt + 1;

    const uint32_t* Kb = Khl + (size_t)bh * S_ * DK_;
    const float*    Vb = Vt  + (size_t)bh * DK_ * S_;

    // Q fragments for the wave's 32 rows, resident across the K-loop
    half8 qhi[2][2], qlo[2][2];
    #pragma unroll
    for (int ni = 0; ni < 2; ++ni) {
        const uint32_t* Qrow =
            Qhl + ((size_t)bh * S_ + q0 + wave * 32 + ni * 16 + c) * DK_;
        #pragma unroll
        for (int ks = 0; ks < 2; ++ks) {
            uint32_t u[8];
            *(uint4*)&u[0] = *(const uint4*)(Qrow + ks * 32 + quad * 8);
            *(uint4*)&u[4] = *(const uint4*)(Qrow + ks * 32 + quad * 8 + 4);
            union { half8 v; uint16_t s[8]; } hi, lo;
            #pragma unroll
            for (int j = 0; j < 8; ++j) {
                hi.s[j] = (uint16_t)(u[j] & 0xffffu);
                lo.s[j] = (uint16_t)(u[j] >> 16);
            }
            qhi[ni][ks] = hi.v; qlo[ni][ks] = lo.v;
        }
    }

    floatx4 acc_o[2][4];
    const floatx4 zero4 = {0.f, 0.f, 0.f, 0.f};
    #pragma unroll
    for (int ni = 0; ni < 2; ++ni)
        #pragma unroll
        for (int d = 0; d < 4; ++d) acc_o[ni][d] = zero4;
    float mrun[2][4], lrun[2][4];
    #pragma unroll
    for (int ni = 0; ni < 2; ++ni)
        #pragma unroll
        for (int r = 0; r < 4; ++r) { mrun[ni][r] = -INFINITY; lrun[ni][r] = 0.f; }

    // staging mapping: K: (row, 16 dks); V: (dk-row, 16 s)
    const int srow = tid >> 2;
    const int soff = (tid & 3) * 16;
    const int ch0  = (tid & 3) * 2;

    uint4 ku[4];
    float4 vf[4];

    auto load_tile = [&](int kt) {
        const uint4* ksrc = (const uint4*)(Kb + (size_t)(kt * 64 + srow) * DK_ + soff);
        ku[0] = ksrc[0]; ku[1] = ksrc[1]; ku[2] = ksrc[2]; ku[3] = ksrc[3];
        const float4* vsrc = (const float4*)(Vb + (size_t)srow * S_ + kt * 64 + soff);
        vf[0] = vsrc[0]; vf[1] = vsrc[1]; vf[2] = vsrc[2]; vf[3] = vsrc[3];
    };
    auto write_tile = [&]() {
        #pragma unroll
        for (int half = 0; half < 2; ++half) {
            uint32_t uu[8];
            *(uint4*)&uu[0] = ku[2 * half];
            *(uint4*)&uu[4] = ku[2 * half + 1];
            union { half8 v; uint16_t s[8]; } hi, lo;
            #pragma unroll
            for (int j = 0; j < 8; ++j) {
                hi.s[j] = (uint16_t)(uu[j] & 0xffffu);
                lo.s[j] = (uint16_t)(uu[j] >> 16);
            }
            *(half8*)&KhiC[ch0 + half][srow][0] = hi.v;
            *(half8*)&KloC[ch0 + half][srow][0] = lo.v;
            union { half8 v; _Float16 h[8]; } vt;
            float4 a = vf[2 * half], b = vf[2 * half + 1];
            vt.h[0] = (_Float16)a.x; vt.h[1] = (_Float16)a.y;
            vt.h[2] = (_Float16)a.z; vt.h[3] = (_Float16)a.w;
            vt.h[4] = (_Float16)b.x; vt.h[5] = (_Float16)b.y;
            vt.h[6] = (_Float16)b.z; vt.h[7] = (_Float16)b.w;
            *(half8*)&VC[ch0 + half][srow][0] = vt.v;
        }
    };

    const int rmax[2] = { q0 + wave * 32 + 15, q0 + wave * 32 + 31 };

    load_tile(0);
    write_tile();

    for (int kt = 0; kt <= ktmax; ++kt) {
        const int k0 = kt * 64;
        __syncthreads();                       // tile kt visible in LDS
        if (kt < ktmax) load_tile(kt + 1);     // prefetch overlaps compute

        // scores for both rowsets first (keeps MFMA pipe fed during softmax)
        floatx4 sc[2][4];
        #pragma unroll
        for (int ni = 0; ni < 2; ++ni) {
            if (k0 <= rmax[ni]) {
                #pragma unroll
                for (int t = 0; t < 4; ++t) {
                    floatx4 s4 = zero4;
                    #pragma unroll
                    for (int ks = 0; ks < 2; ++ks) {
                        half8 kb = *(const half8*)&KhiC[ks * 4 + quad][t * 16 + c][0];
                        half8 kl = *(const half8*)&KloC[ks * 4 + quad][t * 16 + c][0];
                        s4 = __builtin_amdgcn_mfma_f32_16x16x32_f16(qhi[ni][ks], kb, s4, 0, 0, 0);
                        s4 = __builtin_amdgcn_mfma_f32_16x16x32_f16(qhi[ni][ks], kl, s4, 0, 0, 0);
                        s4 = __builtin_amdgcn_mfma_f32_16x16x32_f16(qlo[ni][ks], kb, s4, 0, 0, 0);
                    }
                    sc[ni][t] = s4;
                }
            }
        }

        #pragma unroll
        for (int ni = 0; ni < 2; ++ni) {
            if (k0 > rmax[ni]) continue;       // wave-uniform causal skip
            const int qrow0 = q0 + wave * 32 + ni * 16 + quad * 4;
            #pragma unroll
            for (int t = 0; t < 4; ++t) {
                const int col = k0 + t * 16 + c;
                #pragma unroll
                for (int r = 0; r < 4; ++r) {
                    const float s = sc[ni][t][r] * 0.125f;
                    sc[ni][t][r] = (col <= qrow0 + r) ? s : -INFINITY;
                }
            }
            #pragma unroll
            for (int r = 0; r < 4; ++r) {
                float mx = fmaxf(fmaxf(sc[ni][0][r], sc[ni][1][r]),
                                 fmaxf(sc[ni][2][r], sc[ni][3][r]));
                mx = fmaxf(mx, __shfl_xor(mx, 1, 16));
                mx = fmaxf(mx, __shfl_xor(mx, 2, 16));
                mx = fmaxf(mx, __shfl_xor(mx, 4, 16));
                mx = fmaxf(mx, __shfl_xor(mx, 8, 16));
                const float mnew  = fmaxf(mrun[ni][r], mx);
                const float alpha = __expf(mrun[ni][r] - mnew);
                float ls = 0.f;
                #pragma unroll
                for (int t = 0; t < 4; ++t) {
                    const float p = __expf(sc[ni][t][r] - mnew);
                    sc[ni][t][r] = p;
                    ls += p;
                }
                ls += __shfl_xor(ls, 1, 16);
                ls += __shfl_xor(ls, 2, 16);
                ls += __shfl_xor(ls, 4, 16);
                ls += __shfl_xor(ls, 8, 16);
                lrun[ni][r] = alpha * lrun[ni][r] + ls;
                mrun[ni][r] = mnew;
                #pragma unroll
                for (int d = 0; d < 4; ++d) acc_o[ni][d][r] *= alpha;
            }

            // P: C-layout -> wave-private chunked LDS (f16)
            #pragma unroll
            for (int t = 0; t < 4; ++t)
                #pragma unroll
                for (int r = 0; r < 4; ++r)
                    PC[wave][ni][2 * t + (c >> 3)][quad * 4 + r][c & 7] =
                        (_Float16)sc[ni][t][r];

            // O += P V  (same-wave LDS RAW; compiler orders via lgkmcnt)
            half8 pa0 = *(const half8*)&PC[wave][ni][quad][c][0];
            half8 pa1 = *(const half8*)&PC[wave][ni][4 + quad][c][0];
            #pragma unroll
            for (int d = 0; d < 4; ++d) {
                half8 vb0 = *(const half8*)&VC[quad][d * 16 + c][0];
                half8 vb1 = *(const half8*)&VC[4 + quad][d * 16 + c][0];
                acc_o[ni][d] = __builtin_amdgcn_mfma_f32_16x16x32_f16(pa0, vb0, acc_o[ni][d], 0, 0, 0);
                acc_o[ni][d] = __builtin_amdgcn_mfma_f32_16x16x32_f16(pa1, vb1, acc_o[ni][d], 0, 0, 0);
            }
        }

        __syncthreads();                       // all reads of tile kt done
        if (kt < ktmax) write_tile();          // vmcnt waits land here
    }

    // normalize + write A[B,S,D]
    const int b = bh >> 4, h = bh & 15;
    #pragma unroll
    for (int ni = 0; ni < 2; ++ni)
        #pragma unroll
        for (int r = 0; r < 4; ++r) {
            const float inv = 1.f / lrun[ni][r];
            const int qr = q0 + wave * 32 + ni * 16 + quad * 4 + r;
            float* dst = A + ((size_t)b * S_ + qr) * D_ + h * DK_;
            #pragma unroll
            for (int d = 0; d < 4; ++d)
                dst[d * 16 + c] = acc_o[ni][d][r] * inv;
        }
}

// ---------------------------------------------------------------------------
extern "C" void kernel_launch(void* const* d_in, const int* in_sizes, int n_in,
                              void* d_out, int out_size, void* d_ws, size_t ws_size,
                              hipStream_t stream) {
    const float* q  = (const float*)d_in[0];
    const float* k  = (const float*)d_in[1];
    const float* v  = (const float*)d_in[2];
    const float* Wq = (const float*)d_in[3];
    const float* Wk = (const float*)d_in[4];
    const float* Wv = (const float*)d_in[5];
    const float* Wo = (const float*)d_in[6];
    float* out = (float*)d_out;

    const size_t SZ = (size_t)B_ * S_ * D_;   // 8,388,608 elements
    float* wsf = (float*)d_ws;
    uint32_t* Qhl = (uint32_t*)wsf;            // packed f16 hi/lo [B,H,S,DK]
    uint32_t* Khl = (uint32_t*)(wsf + SZ);     // packed f16 hi/lo [B,H,S,DK]
    float*    Vt  = wsf + 2 * SZ;              // fp32 [B,H,DK,S]
    float*    A   = wsf + 3 * SZ;              // fp32 [B,S,D]

    dim3 gb(NR_ / GBN, D_ / GBM);   // 64 x 16
    gemm_xwt_mfma<<<gb, 256, 0, stream>>>(q, Wq, Qhl, 1);
    gemm_xwt_mfma<<<gb, 256, 0, stream>>>(k, Wk, Khl, 1);
    gemm_xwt_mfma<<<gb, 256, 0, stream>>>(v, Wv, Vt, 2);

    dim3 ga(S_ / 128, B_ * H_);     // 16 x 64
    attn_mfma<<<ga, 256, 0, stream>>>(Qhl, Khl, Vt, A);

    gemm_xwt_mfma<<<gb, 256, 0, stream>>>(A, Wo, out, 0);
}

// Round 7
// 693.459 us; speedup vs baseline: 3.6298x; 1.1556x over previous
//
#include <hip/hip_runtime.h>
#include <math.h>
#include <stdint.h>

#define B_  4
#define S_  2048
#define D_  1024
#define H_  16
#define DK_ 64
#define NR_ (B_ * S_)   // 8192 rows

typedef _Float16 half8  __attribute__((ext_vector_type(8)));
typedef _Float16 half4  __attribute__((ext_vector_type(4)));
typedef float    floatx4 __attribute__((ext_vector_type(4)));

// ---------------------------------------------------------------------------
// GEMM: out = X @ W^T via split-f16 MFMA (fp32-accurate). Validated r4-r6.
// Epilogue modes:
//   0: fp32 [N x M] row-major                       (Wo projection -> d_out)
//   1: packed u32 {lo16,hi16} f16 split, [B,H,S,DK]  (Q,K projections)
//   2: fp32 transposed head-split [B,H,DK,S]         (V projection, float4)
// ---------------------------------------------------------------------------
#define GBN 128
#define GBM 64
#define GBK 32
#define LDH 40

__global__ __launch_bounds__(256)
void gemm_xwt_mfma(const float* __restrict__ X, const float* __restrict__ W,
                   void* __restrict__ outp, int mode) {
    __shared__ __align__(16) _Float16 Xhi[GBN][LDH];
    __shared__ __align__(16) _Float16 Xlo[GBN][LDH];
    __shared__ __align__(16) _Float16 Whi[GBM][LDH];
    __shared__ __align__(16) _Float16 Wlo[GBM][LDH];
    const int K = D_;

    const int tid  = threadIdx.x;
    const int wave = tid >> 6;
    const int lane = tid & 63;
    const int row16 = lane & 15;
    const int quad  = lane >> 4;
    const int n0 = blockIdx.x * GBN;
    const int m0 = blockIdx.y * GBM;

    floatx4 acc[2][4];
    const floatx4 zero4 = {0.f, 0.f, 0.f, 0.f};
    #pragma unroll
    for (int i = 0; i < 2; ++i)
        #pragma unroll
        for (int j = 0; j < 4; ++j) acc[i][j] = zero4;

    for (int k0 = 0; k0 < K; k0 += GBK) {
        __syncthreads();
        #pragma unroll
        for (int i = 0; i < 4; ++i) {
            const int t   = i * 256 + tid;
            const int row = t >> 3;
            const int c4  = (t & 7) << 2;
            float4 xv = *(const float4*)(X + (size_t)(n0 + row) * K + k0 + c4);
            float f[4] = {xv.x, xv.y, xv.z, xv.w};
            #pragma unroll
            for (int c = 0; c < 4; ++c) {
                _Float16 h = (_Float16)f[c];
                Xhi[row][c4 + c] = h;
                Xlo[row][c4 + c] = (_Float16)(f[c] - (float)h);
            }
        }
        #pragma unroll
        for (int i = 0; i < 2; ++i) {
            const int t   = i * 256 + tid;
            const int row = t >> 3;
            const int c4  = (t & 7) << 2;
            float4 wv = *(const float4*)(W + (size_t)(m0 + row) * K + k0 + c4);
            float f[4] = {wv.x, wv.y, wv.z, wv.w};
            #pragma unroll
            for (int c = 0; c < 4; ++c) {
                _Float16 h = (_Float16)f[c];
                Whi[row][c4 + c] = h;
                Wlo[row][c4 + c] = (_Float16)(f[c] - (float)h);
            }
        }
        __syncthreads();

        half8 a_hi[2], a_lo[2], b_hi[4], b_lo[4];
        #pragma unroll
        for (int ni = 0; ni < 2; ++ni) {
            const int r = wave * 32 + ni * 16 + row16;
            a_hi[ni] = *(const half8*)&Xhi[r][quad * 8];
            a_lo[ni] = *(const half8*)&Xlo[r][quad * 8];
        }
        #pragma unroll
        for (int mj = 0; mj < 4; ++mj) {
            const int r = mj * 16 + row16;
            b_hi[mj] = *(const half8*)&Whi[r][quad * 8];
            b_lo[mj] = *(const half8*)&Wlo[r][quad * 8];
        }

        #pragma unroll
        for (int ni = 0; ni < 2; ++ni)
            #pragma unroll
            for (int mj = 0; mj < 4; ++mj) {
                acc[ni][mj] = __builtin_amdgcn_mfma_f32_16x16x32_f16(
                    a_hi[ni], b_hi[mj], acc[ni][mj], 0, 0, 0);
                acc[ni][mj] = __builtin_amdgcn_mfma_f32_16x16x32_f16(
                    a_hi[ni], b_lo[mj], acc[ni][mj], 0, 0, 0);
                acc[ni][mj] = __builtin_amdgcn_mfma_f32_16x16x32_f16(
                    a_lo[ni], b_hi[mj], acc[ni][mj], 0, 0, 0);
            }
    }

    #pragma unroll
    for (int ni = 0; ni < 2; ++ni)
        #pragma unroll
        for (int mj = 0; mj < 4; ++mj) {
            if (mode == 2) {
                const int s  = n0 + wave * 32 + ni * 16 + quad * 4;
                const int b  = s >> 11;
                const int sr = s & (S_ - 1);
                const int m  = m0 + mj * 16 + row16;
                const int h  = m >> 6;
                const int dk = m & 63;
                float4 v4 = make_float4(acc[ni][mj][0], acc[ni][mj][1],
                                        acc[ni][mj][2], acc[ni][mj][3]);
                *(float4*)((float*)outp +
                           (((size_t)b * H_ + h) * DK_ + dk) * S_ + sr) = v4;
            } else {
                #pragma unroll
                for (int rg = 0; rg < 4; ++rg) {
                    const int n = n0 + wave * 32 + ni * 16 + quad * 4 + rg;
                    const int m = m0 + mj * 16 + row16;
                    const float v = acc[ni][mj][rg];
                    if (mode == 0) {
                        ((float*)outp)[(size_t)n * D_ + m] = v;
                    } else {
                        const int b  = n >> 11;
                        const int s  = n & (S_ - 1);
                        const int h  = m >> 6;
                        const int dk = m & 63;
                        union { _Float16 h16; uint16_t u; } hi, lo;
                        hi.h16 = (_Float16)v;
                        lo.h16 = (_Float16)(v - (float)hi.h16);
                        uint32_t u = ((uint32_t)lo.u << 16) | (uint32_t)hi.u;
                        ((uint32_t*)outp)[(((size_t)b * H_ + h) * S_ + s) * DK_ + dk] = u;
                    }
                }
            }
        }
}

// ---------------------------------------------------------------------------
// MFMA flash attention v3: transposed-score formulation.
//   S^T = K·Q^T  (swap MFMA operands; C-layout col = q-row = lane&15)
//   -> softmax row reduction = in-lane over 16 k-values + 2 shuffles/tile
//   O^T = V^T·P^T (A = V^T rows from [B,H,DK,S]; B = P rows via LDS)
// Block = (b,h) x 64 q-rows, 4 waves; wave owns 16 q-rows (q = q0+16w+c).
// K/V LDS: XOR-swizzled 16B chunks (chunk ^ (row&7)) -> conflict-floor b128.
// Diagonal-tile-only masking; t>wave tiles on diagonal skipped entirely.
// Register prefetch of tile kt+1 overlaps compute.
// ---------------------------------------------------------------------------
__global__ __launch_bounds__(256)
void attn_mfma(const uint32_t* __restrict__ Qhl, const uint32_t* __restrict__ Khl,
               const float* __restrict__ Vt, float* __restrict__ A) {
    __shared__ __align__(16) _Float16 KhiC[64][64];
    __shared__ __align__(16) _Float16 KloC[64][64];
    __shared__ __align__(16) _Float16 VC[64][64];
    __shared__ __align__(16) _Float16 PCT[4][16][72];   // [wave][q][k]

    const int bh = blockIdx.y;
    const int qt = (int)(gridDim.x - 1) - (int)blockIdx.x;  // heavy tiles first
    const int q0 = qt * 64;
    const int tid  = threadIdx.x;
    const int wave = tid >> 6;
    const int lane = tid & 63;
    const int c    = lane & 15;
    const int quad = lane >> 4;

    const uint32_t* Kb = Khl + (size_t)bh * S_ * DK_;
    const float*    Vb = Vt  + (size_t)bh * DK_ * S_;

    // Q fragment (B-operand): lane holds q-row (q0+16w+c), k = ks*32+quad*8+j
    half8 qhi[2], qlo[2];
    {
        const uint32_t* Qrow = Qhl + ((size_t)bh * S_ + q0 + wave * 16 + c) * DK_;
        #pragma unroll
        for (int ks = 0; ks < 2; ++ks) {
            uint32_t u[8];
            *(uint4*)&u[0] = *(const uint4*)(Qrow + ks * 32 + quad * 8);
            *(uint4*)&u[4] = *(const uint4*)(Qrow + ks * 32 + quad * 8 + 4);
            union { half8 v; uint16_t s[8]; } hi, lo;
            #pragma unroll
            for (int j = 0; j < 8; ++j) {
                hi.s[j] = (uint16_t)(u[j] & 0xffffu);
                lo.s[j] = (uint16_t)(u[j] >> 16);
            }
            qhi[ks] = hi.v; qlo[ks] = lo.v;
        }
    }

    floatx4 acc_o[4];   // O^T: acc_o[dt][r] = O[q=lane-col][dk=dt*16+quad*4+r]
    const floatx4 zero4 = {0.f, 0.f, 0.f, 0.f};
    #pragma unroll
    for (int dt = 0; dt < 4; ++dt) acc_o[dt] = zero4;
    float mrun = -INFINITY, lrun = 0.f;

    // staging: thread -> (row srow, 16-elem segment); chunk = 8 halves = 16 B
    const int srow = tid >> 2;
    const int soff = (tid & 3) * 16;
    const int ch0  = (tid & 3) * 2;

    uint4 ku[4];
    float4 vf[4];
    auto load_tile = [&](int kt) {
        const uint4* ksrc = (const uint4*)(Kb + (size_t)(kt * 64 + srow) * DK_ + soff);
        ku[0] = ksrc[0]; ku[1] = ksrc[1]; ku[2] = ksrc[2]; ku[3] = ksrc[3];
        const float4* vsrc = (const float4*)(Vb + (size_t)srow * S_ + kt * 64 + soff);
        vf[0] = vsrc[0]; vf[1] = vsrc[1]; vf[2] = vsrc[2]; vf[3] = vsrc[3];
    };
    auto write_tile = [&]() {
        #pragma unroll
        for (int hf = 0; hf < 2; ++hf) {
            const int swz = ((ch0 + hf) ^ (srow & 7)) * 8;
            uint32_t uu[8];
            *(uint4*)&uu[0] = ku[2 * hf];
            *(uint4*)&uu[4] = ku[2 * hf + 1];
            union { half8 v; uint16_t s[8]; } hi, lo;
            #pragma unroll
            for (int j = 0; j < 8; ++j) {
                hi.s[j] = (uint16_t)(uu[j] & 0xffffu);
                lo.s[j] = (uint16_t)(uu[j] >> 16);
            }
            *(half8*)&KhiC[srow][swz] = hi.v;
            *(half8*)&KloC[srow][swz] = lo.v;
            union { half8 v; _Float16 h[8]; } vt;
            float4 a = vf[2 * hf], b = vf[2 * hf + 1];
            vt.h[0] = (_Float16)a.x; vt.h[1] = (_Float16)a.y;
            vt.h[2] = (_Float16)a.z; vt.h[3] = (_Float16)a.w;
            vt.h[4] = (_Float16)b.x; vt.h[5] = (_Float16)b.y;
            vt.h[6] = (_Float16)b.z; vt.h[7] = (_Float16)b.w;
            *(half8*)&VC[srow][swz] = vt.v;
        }
    };

    const int qmy = q0 + wave * 16 + c;   // this lane's q-row
    const floatx4 neg4 = {-INFINITY, -INFINITY, -INFINITY, -INFINITY};

    load_tile(0);
    write_tile();

    for (int kt = 0; kt <= qt; ++kt) {
        const int k0 = kt * 64;
        const bool diag = (kt == qt);
        __syncthreads();                     // tile kt visible in LDS
        if (kt < qt) load_tile(kt + 1);      // prefetch overlaps compute

        // S^T tiles: sc[t][r] = S[q=qmy][k = k0 + t*16 + quad*4 + r] (unscaled)
        floatx4 sc[4];
        #pragma unroll
        for (int t = 0; t < 4; ++t) {
            if (diag && t > wave) { sc[t] = neg4; continue; }
            floatx4 s4 = zero4;
            const int krow = t * 16 + c;
            #pragma unroll
            for (int ks = 0; ks < 2; ++ks) {
                const int swz = ((ks * 4 + quad) ^ (krow & 7)) * 8;
                half8 kb = *(const half8*)&KhiC[krow][swz];
                half8 kl = *(const half8*)&KloC[krow][swz];
                s4 = __builtin_amdgcn_mfma_f32_16x16x32_f16(kb, qhi[ks], s4, 0, 0, 0);
                s4 = __builtin_amdgcn_mfma_f32_16x16x32_f16(kl, qhi[ks], s4, 0, 0, 0);
                s4 = __builtin_amdgcn_mfma_f32_16x16x32_f16(kb, qlo[ks], s4, 0, 0, 0);
            }
            #pragma unroll
            for (int r = 0; r < 4; ++r) s4[r] *= 0.125f;
            if (diag && t == wave) {
                #pragma unroll
                for (int r = 0; r < 4; ++r) {
                    const int k = k0 + t * 16 + quad * 4 + r;
                    if (k > qmy) s4[r] = -INFINITY;
                }
            }
            sc[t] = s4;
        }

        // online softmax: in-lane max over 16, 2 cross-quad shuffles
        float mx = -INFINITY;
        #pragma unroll
        for (int t = 0; t < 4; ++t)
            #pragma unroll
            for (int r = 0; r < 4; ++r) mx = fmaxf(mx, sc[t][r]);
        mx = fmaxf(mx, __shfl_xor(mx, 16));
        mx = fmaxf(mx, __shfl_xor(mx, 32));
        const float mnew  = fmaxf(mrun, mx);
        const float alpha = __expf(mrun - mnew);
        float ls = 0.f;
        #pragma unroll
        for (int t = 0; t < 4; ++t) {
            half4 p4;
            #pragma unroll
            for (int r = 0; r < 4; ++r) {
                const float p = __expf(sc[t][r] - mnew);
                ls += p;
                p4[r] = (_Float16)p;
            }
            // P^T store: PCT[wave][q=c][k-local = t*16+quad*4 .. +3]
            *(half4*)&PCT[wave][c][t * 16 + quad * 4] = p4;
        }
        lrun = alpha * lrun + ls;
        mrun = mnew;
        #pragma unroll
        for (int dt = 0; dt < 4; ++dt)
            #pragma unroll
            for (int r = 0; r < 4; ++r) acc_o[dt][r] *= alpha;

        // O^T += V^T P^T  (A-frag = V^T rows, B-frag = P rows; same-wave RAW)
        #pragma unroll
        for (int kc = 0; kc < 2; ++kc) {
            if (diag && kc == 1 && wave < 2) continue;   // P chunk all-zero
            half8 pb = *(const half8*)&PCT[wave][c][kc * 32 + quad * 8];
            #pragma unroll
            for (int dt = 0; dt < 4; ++dt) {
                const int vrow = dt * 16 + c;
                const int swz = ((kc * 4 + quad) ^ (vrow & 7)) * 8;
                half8 va = *(const half8*)&VC[vrow][swz];
                acc_o[dt] = __builtin_amdgcn_mfma_f32_16x16x32_f16(va, pb, acc_o[dt], 0, 0, 0);
            }
        }

        __syncthreads();                     // all reads of tile kt done
        if (kt < qt) write_tile();
    }

    // final l across quads, normalize, write A[B,S,D] (float4 per d-tile)
    float l = lrun;
    l += __shfl_xor(l, 16);
    l += __shfl_xor(l, 32);
    const float inv = 1.f / l;
    const int b = bh >> 4, h = bh & 15;
    float* dst = A + ((size_t)b * S_ + qmy) * D_ + h * DK_;
    #pragma unroll
    for (int dt = 0; dt < 4; ++dt) {
        float4 o4 = make_float4(acc_o[dt][0] * inv, acc_o[dt][1] * inv,
                                acc_o[dt][2] * inv, acc_o[dt][3] * inv);
        *(float4*)(dst + dt * 16 + quad * 4) = o4;
    }
}

// ---------------------------------------------------------------------------
extern "C" void kernel_launch(void* const* d_in, const int* in_sizes, int n_in,
                              void* d_out, int out_size, void* d_ws, size_t ws_size,
                              hipStream_t stream) {
    const float* q  = (const float*)d_in[0];
    const float* k  = (const float*)d_in[1];
    const float* v  = (const float*)d_in[2];
    const float* Wq = (const float*)d_in[3];
    const float* Wk = (const float*)d_in[4];
    const float* Wv = (const float*)d_in[5];
    const float* Wo = (const float*)d_in[6];
    float* out = (float*)d_out;

    const size_t SZ = (size_t)B_ * S_ * D_;   // 8,388,608 elements
    float* wsf = (float*)d_ws;
    uint32_t* Qhl = (uint32_t*)wsf;            // packed f16 hi/lo [B,H,S,DK]
    uint32_t* Khl = (uint32_t*)(wsf + SZ);     // packed f16 hi/lo [B,H,S,DK]
    float*    Vt  = wsf + 2 * SZ;              // fp32 [B,H,DK,S]
    float*    A   = wsf + 3 * SZ;              // fp32 [B,S,D]

    dim3 gb(NR_ / GBN, D_ / GBM);   // 64 x 16
    gemm_xwt_mfma<<<gb, 256, 0, stream>>>(q, Wq, Qhl, 1);
    gemm_xwt_mfma<<<gb, 256, 0, stream>>>(k, Wk, Khl, 1);
    gemm_xwt_mfma<<<gb, 256, 0, stream>>>(v, Wv, Vt, 2);

    dim3 ga(S_ / 64, B_ * H_);      // 32 x 64
    attn_mfma<<<ga, 256, 0, stream>>>(Qhl, Khl, Vt, A);

    gemm_xwt_mfma<<<gb, 256, 0, stream>>>(A, Wo, out, 0);
}